// Round 1
// baseline (223.994 us; speedup 1.0000x reference)
//
#include <hip/hip_runtime.h>
#include <hip/hip_bf16.h>

typedef __hip_bfloat16 bf16;
typedef short bf16x8 __attribute__((ext_vector_type(8)));
typedef float f32x4 __attribute__((ext_vector_type(4)));

#define BM 128
#define BN 128
#define BK 32

__device__ __forceinline__ void gload_lds16(const void* g, void* l) {
    __builtin_amdgcn_global_load_lds(
        (const __attribute__((address_space(1))) void*)g,
        (__attribute__((address_space(3))) void*)l, 16, 0, 0);
}

// MODE 0: C_bf16 = A @ B^T-form            (projection)
// MODE 1: C_bf16 = scale * (A @ B^T-form), skip tiles fully above diagonal (scores)
// MODE 2: C_f32  = A @ B^T-form + Res_bf16, K clipped to brow+BM (PV + residual)
template<int MODE>
__launch_bounds__(256, 2)
__global__ void gemm128(const bf16* __restrict__ A, const bf16* __restrict__ B,
                        bf16* __restrict__ Cb, float* __restrict__ Cf,
                        const bf16* __restrict__ Res,
                        int lda, int ldb, int ldc, int K,
                        long sA, long sB, long sC, long sR,
                        float scale)
{
    const int bj = blockIdx.x;   // col tile
    const int bi = blockIdx.y;   // row tile
    if (MODE == 1 && bj > bi) return;
    const int bz = blockIdx.z;
    A += (size_t)bz * sA;
    B += (size_t)bz * sB;
    const int brow = bi * BM, bcol = bj * BN;

    __shared__ __align__(16) bf16 lA[BM][BK];   // 8 KB
    __shared__ __align__(16) bf16 lB[BN][BK];   // 8 KB

    const int tid  = threadIdx.x;
    const int lane = tid & 63;
    const int w    = tid >> 6;       // 4 waves
    const int wr   = w >> 1, wc = w & 1;

    f32x4 acc[4][4] = {};

    // staging: each wave stages 2x16 rows of A and of B, 16B per lane
    const int srow = lane >> 2;          // 0..15
    const int scol = (lane & 3) * 8;     // element offset (8 bf16 = 16B)
    const bf16* gA0 = A + (size_t)(brow + w * 32 + srow) * lda + scol;
    const bf16* gB0 = B + (size_t)(bcol + w * 32 + srow) * ldb + scol;
    bf16* lA0 = &lA[w * 32 + srow][scol];
    bf16* lB0 = &lB[w * 32 + srow][scol];

    int kmax = K;
    if (MODE == 2) kmax = min(K, brow + BM);

    const int fr = lane & 15;   // frag row/col within 16
    const int fq = lane >> 4;   // k-group / row-quad

    for (int k0 = 0; k0 < kmax; k0 += BK) {
        gload_lds16(gA0 + k0,                  lA0);
        gload_lds16(gA0 + k0 + (size_t)16*lda, lA0 + 16 * BK);
        gload_lds16(gB0 + k0,                  lB0);
        gload_lds16(gB0 + k0 + (size_t)16*ldb, lB0 + 16 * BK);
        __syncthreads();

        bf16x8 af[4], bfr[4];
        #pragma unroll
        for (int m = 0; m < 4; m++)
            af[m] = *(const bf16x8*)&lA[wr * 64 + m * 16 + fr][fq * 8];
        #pragma unroll
        for (int n = 0; n < 4; n++)
            bfr[n] = *(const bf16x8*)&lB[wc * 64 + n * 16 + fr][fq * 8];
        #pragma unroll
        for (int m = 0; m < 4; m++)
            #pragma unroll
            for (int n = 0; n < 4; n++)
                acc[m][n] = __builtin_amdgcn_mfma_f32_16x16x32_bf16(
                                af[m], bfr[n], acc[m][n], 0, 0, 0);
        __syncthreads();
    }

    // epilogue: C/D layout col = lane&15, row = (lane>>4)*4 + j
    if (MODE == 0 || MODE == 1) {
        bf16* C = Cb + (size_t)bz * sC;
        #pragma unroll
        for (int m = 0; m < 4; m++) {
            const int row = brow + wr * 64 + m * 16 + fq * 4;
            #pragma unroll
            for (int n = 0; n < 4; n++) {
                const int col = bcol + wc * 64 + n * 16 + fr;
                #pragma unroll
                for (int j = 0; j < 4; j++)
                    C[(size_t)(row + j) * ldc + col] =
                        __float2bfloat16(acc[m][n][j] * scale);
            }
        }
    } else {
        float* C = Cf + (size_t)bz * sC;
        const bf16* R = Res + (size_t)bz * sR;
        #pragma unroll
        for (int m = 0; m < 4; m++) {
            const int row = brow + wr * 64 + m * 16 + fq * 4;
            #pragma unroll
            for (int n = 0; n < 4; n++) {
                const int col = bcol + wc * 64 + n * 16 + fr;
                #pragma unroll
                for (int j = 0; j < 4; j++)
                    C[(size_t)(row + j) * ldc + col] = acc[m][n][j] +
                        __bfloat162float(R[(size_t)(row + j) * ldc + col]);
            }
        }
    }
}

// fp32 -> bf16 convert of q,k,v into stacked [3*8192][1024] (q rows first)
struct bh4 { bf16 h[4]; };
__global__ void convert_qkv(const float* __restrict__ q, const float* __restrict__ k,
                            const float* __restrict__ v, bf16* __restrict__ Xb)
{
    const int N4 = 8192 * 1024 / 4;
    const int total = 3 * N4;
    for (int i = blockIdx.x * 256 + threadIdx.x; i < total; i += gridDim.x * 256) {
        const int t = i / N4, j = i - t * N4;
        const float4* src = (t == 0) ? (const float4*)q
                          : (t == 1) ? (const float4*)k : (const float4*)v;
        float4 x = src[j];
        bh4 o;
        o.h[0] = __float2bfloat16(x.x);
        o.h[1] = __float2bfloat16(x.y);
        o.h[2] = __float2bfloat16(x.z);
        o.h[3] = __float2bfloat16(x.w);
        ((bh4*)Xb)[i] = o;
    }
}

// Wt[n][k] = bf16(wi[k][n]),  1024x1024
__global__ void transpose_wi(const float* __restrict__ wi, bf16* __restrict__ Wt)
{
    __shared__ float t[32][33];
    const int n0 = blockIdx.x * 32, k0 = blockIdx.y * 32;
    const int lx = threadIdx.x & 31, ly = threadIdx.x >> 5;   // 8 rows
    for (int i = ly; i < 32; i += 8)
        t[i][lx] = wi[(size_t)(k0 + i) * 1024 + n0 + lx];
    __syncthreads();
    for (int i = ly; i < 32; i += 8)
        Wt[(size_t)(n0 + i) * 1024 + k0 + lx] = __float2bfloat16(t[lx][i]);
}

// vpT[b][d][s] = vp[b][s][d]
__global__ void transpose_vp(const bf16* __restrict__ vp, bf16* __restrict__ vpT)
{
    __shared__ bf16 t[32][33];
    const int b = blockIdx.z;
    const int d0 = blockIdx.x * 32, s0 = blockIdx.y * 32;
    const bf16* src = vp + (size_t)b * 2048 * 1024;
    bf16* dst = vpT + (size_t)b * 1024 * 2048;
    const int lx = threadIdx.x & 31, ly = threadIdx.x >> 5;
    for (int i = ly; i < 32; i += 8)
        t[i][lx] = src[(size_t)(s0 + i) * 1024 + d0 + lx];
    __syncthreads();
    for (int i = ly; i < 32; i += 8)
        dst[(size_t)(d0 + i) * 2048 + s0 + lx] = t[lx][i];
}

// causal row softmax in-place on bf16 scores; zero-fill to 128-aligned boundary
__launch_bounds__(256)
__global__ void softmax_causal(bf16* __restrict__ P)
{
    const int r = blockIdx.x, b = blockIdx.y;
    bf16* row = P + ((size_t)b * 2048 + r) * 2048;
    __shared__ float sm[2048];
    __shared__ float red[8];
    const int tid = threadIdx.x;
    const int nv = r + 1;

    float lmax = -1e30f;
    for (int k = tid; k < nv; k += 256) {
        float s = __bfloat162float(row[k]);
        sm[k] = s;
        lmax = fmaxf(lmax, s);
    }
    for (int o = 32; o; o >>= 1) lmax = fmaxf(lmax, __shfl_down(lmax, o));
    if ((tid & 63) == 0) red[tid >> 6] = lmax;
    __syncthreads();
    const float m = fmaxf(fmaxf(red[0], red[1]), fmaxf(red[2], red[3]));

    float lsum = 0.f;
    for (int k = tid; k < nv; k += 256) {
        float e = __expf(sm[k] - m);
        sm[k] = e;
        lsum += e;
    }
    for (int o = 32; o; o >>= 1) lsum += __shfl_down(lsum, o);
    if ((tid & 63) == 0) red[4 + (tid >> 6)] = lsum;
    __syncthreads();
    const float inv = 1.0f / (red[4] + red[5] + red[6] + red[7]);

    const int rup = (r / 128 + 1) * 128;
    for (int k = tid; k < rup; k += 256) {
        float p = (k < nv) ? sm[k] * inv : 0.0f;
        row[k] = __float2bfloat16(p);
    }
}

extern "C" void kernel_launch(void* const* d_in, const int* in_sizes, int n_in,
                              void* d_out, int out_size, void* d_ws, size_t ws_size,
                              hipStream_t stream)
{
    const float* v  = (const float*)d_in[0];
    const float* k  = (const float*)d_in[1];
    const float* q  = (const float*)d_in[2];
    const float* wi = (const float*)d_in[3];
    // d_in[4] = causal mask (structure known; unused)
    float* out = (float*)d_out;

    char* ws = (char*)d_ws;
    const size_t WT_OFF   = 0;                      // 2 MB
    const size_t PROJ_OFF = WT_OFF + (2u << 20);    // 50.33 MB
    const size_t VPT_OFF  = PROJ_OFF + (size_t)24576 * 1024 * 2;
    const size_t XB_OFF   = VPT_OFF + (size_t)4 * 1024 * 2048 * 2;

    bf16* Wt   = (bf16*)(ws + WT_OFF);
    bf16* proj = (bf16*)(ws + PROJ_OFF);    // [q(8192) | k(8192) | v(8192)] x 1024
    bf16* vpT  = (bf16*)(ws + VPT_OFF);     // [4][1024][2048]
    bf16* Xb   = (bf16*)(ws + XB_OFF);      // [24576][1024], reused as P
    bf16* P    = Xb;                        // [4][2048][2048] (aliases Xb; Xb dead by then)

    bf16* qp_b = proj;
    bf16* kp_b = proj + (size_t)8192 * 1024;
    bf16* vp_b = proj + (size_t)16384 * 1024;

    convert_qkv<<<2048, 256, 0, stream>>>(q, k, v, Xb);
    transpose_wi<<<dim3(32, 32), 256, 0, stream>>>(wi, Wt);

    // projection: [24576,1024] = Xb @ Wt^T-form
    gemm128<0><<<dim3(8, 192, 1), 256, 0, stream>>>(
        Xb, Wt, proj, nullptr, nullptr,
        1024, 1024, 1024, 1024, 0, 0, 0, 0, 1.0f);

    transpose_vp<<<dim3(32, 64, 4), 256, 0, stream>>>(vp_b, vpT);

    // scores: per batch [2048,2048] = qp @ kp^T, * 1/sqrt(1024), causal skip
    gemm128<1><<<dim3(16, 16, 4), 256, 0, stream>>>(
        qp_b, kp_b, P, nullptr, nullptr,
        1024, 1024, 2048, 1024,
        (long)2048 * 1024, (long)2048 * 1024, (long)2048 * 2048, 0, 0.03125f);

    softmax_causal<<<dim3(2048, 4), 256, 0, stream>>>(P);

    // out: per batch [2048,1024] = P @ vpT^T-form + qp (residual), fp32
    gemm128<2><<<dim3(8, 16, 4), 256, 0, stream>>>(
        P, vpT, nullptr, out, qp_b,
        2048, 2048, 1024, 2048,
        (long)2048 * 2048, (long)1024 * 2048, (long)2048 * 1024, (long)2048 * 1024, 1.0f);
}

// Round 2
// 208.913 us; speedup vs baseline: 1.0722x; 1.0722x over previous
//
#include <hip/hip_runtime.h>
#include <hip/hip_bf16.h>

typedef __hip_bfloat16 bf16;
typedef short bf16x8 __attribute__((ext_vector_type(8)));
typedef float f32x4 __attribute__((ext_vector_type(4)));

#define HT 16384   // half-tile bytes: 128 rows x 64 cols bf16
#define SLOT_A0 0
#define SLOT_A1 1
#define SLOT_B0 2
#define SLOT_B1 3

__device__ __forceinline__ void gload16(const void* g, void* l) {
    __builtin_amdgcn_global_load_lds(
        (const __attribute__((address_space(1))) void*)g,
        (__attribute__((address_space(3))) void*)l, 16, 0, 0);
}

// Stage one 128x64 half-tile: linear LDS dest (global_load_lds requirement),
// source pre-swizzled with the involution  L ^= ((L>>7)&7)<<4  so that
// swizzled ds_reads come back bank-conflict-free.
__device__ __forceinline__ void stage_half(char* lds, const bf16* src, int ld,
                                           int rowbase, int k0, int buf, int slot,
                                           int tid)
{
    char* dst = lds + (size_t)(buf * 4 + slot) * HT + tid * 16;
    const int sub = tid >> 3;
    const int cb  = ((tid & 7) ^ (sub & 7)) << 4;
    #pragma unroll
    for (int p = 0; p < 2; ++p) {
        const int row = p * 64 + sub;
        const char* g = (const char*)(src + (size_t)(rowbase + row) * ld + k0) + cb;
        gload16(g, dst + p * 8192);
    }
}

// read one MFMA A/B fragment (8 bf16 = 16B) with the read-side swizzle
__device__ __forceinline__ bf16x8 ldsfrag(const char* lds, int buf, int slot,
                                          int row, int ks, int cb0)
{
    return *(const bf16x8*)(lds + (size_t)(buf * 4 + slot) * HT
                            + row * 128 + (cb0 ^ (ks << 6)));
}

// MODE 0: C_bf16 = A @ B^T-form                       (projection)
// MODE 1: C_bf16 = scale * (A @ B^T-form), skip bj>bi (scores, causal)
// MODE 2: C_f32  = A @ B^T-form + Res_bf16, K clipped (PV + residual)
template<int MODE>
__launch_bounds__(512, 2)
__global__ void gemm256(const bf16* __restrict__ A, const bf16* __restrict__ B,
                        bf16* __restrict__ Cb, float* __restrict__ Cf,
                        const bf16* __restrict__ Res,
                        int lda, int ldb, int ldc, int K,
                        long sA, long sB, long sC, long sR, float scale)
{
    extern __shared__ char lds[];
    // XCD-chunked swizzle (nwg % 8 == 0 for all our grids)
    const int gx = gridDim.x;
    int id = blockIdx.y * gx + blockIdx.x;
    const int chunk = (gridDim.y * gx) >> 3;
    id = (id & 7) * chunk + (id >> 3);
    const int bj = id % gx, bi = id / gx;
    if (MODE == 1 && bj > bi) return;
    const int bz = blockIdx.z;
    A += (size_t)bz * sA;
    B += (size_t)bz * sB;
    const int brow = bi * 256, bcol = bj * 256;

    const int tid  = threadIdx.x;
    const int lane = tid & 63;
    const int w    = tid >> 6;            // 8 waves
    const int wm   = w >> 2, wn = w & 3;  // 2 x 4
    const int fr   = lane & 15, fq = lane >> 4;
    const int cb0  = ((fr & 7) ^ fq) << 4;
    const int slotA = wm;                 // wave's A half-tile
    const int slotB = 2 + (wn >> 1);      // wave's B half-tile
    const int rB    = (wn & 1) * 64;      // row offset inside B half

    const int kmax = (MODE == 2) ? min(K, brow + 256) : K;
    const int NT   = kmax >> 6;           // >= 4 for all our shapes

    f32x4 acc[8][4] = {};
    bf16x8 af[4][2], bv[4][2];

    // prologue: tile0 fully + tile1 {B0, A0}; complete tile0, keep 4 in flight
    stage_half(lds, B, ldb, bcol,       0,  0, SLOT_B0, tid);
    stage_half(lds, A, lda, brow,       0,  0, SLOT_A0, tid);
    stage_half(lds, B, ldb, bcol + 128, 0,  0, SLOT_B1, tid);
    stage_half(lds, A, lda, brow + 128, 0,  0, SLOT_A1, tid);
    stage_half(lds, B, ldb, bcol,       64, 1, SLOT_B0, tid);
    stage_half(lds, A, lda, brow,       64, 1, SLOT_A0, tid);
    asm volatile("s_waitcnt vmcnt(4)" ::: "memory");
    __builtin_amdgcn_s_barrier();

#define QUAD(mh, nh)                                                          \
    _Pragma("unroll") for (int m = 0; m < 4; ++m)                             \
    _Pragma("unroll") for (int n = 0; n < 2; ++n)                             \
    _Pragma("unroll") for (int ks = 0; ks < 2; ++ks)                          \
        acc[(mh)*4+m][(nh)*2+n] = __builtin_amdgcn_mfma_f32_16x16x32_bf16(    \
            af[m][ks], bv[(nh)*2+n][ks], acc[(mh)*4+m][(nh)*2+n], 0, 0, 0);

    for (int t = 0; t < NT; ++t) {
        const int buf = t & 1, nbuf = buf ^ 1;
        const int k1 = min(t + 1, NT - 1) << 6;   // source clamp: dead-slot dummies
        const int k2 = min(t + 2, NT - 1) << 6;

        // ---- phase 0: A mf0-3 + B nf0-1 reads; stage (t+1).B1
        #pragma unroll
        for (int m = 0; m < 4; ++m)
            #pragma unroll
            for (int ks = 0; ks < 2; ++ks)
                af[m][ks] = ldsfrag(lds, buf, slotA, m * 16 + fr, ks, cb0);
        #pragma unroll
        for (int n = 0; n < 2; ++n)
            #pragma unroll
            for (int ks = 0; ks < 2; ++ks)
                bv[n][ks] = ldsfrag(lds, buf, slotB, rB + n * 16 + fr, ks, cb0);
        stage_half(lds, B, ldb, bcol + 128, k1, nbuf, SLOT_B1, tid);
        __builtin_amdgcn_s_barrier();
        __builtin_amdgcn_s_setprio(1);
        QUAD(0, 0)
        __builtin_amdgcn_s_setprio(0);
        __builtin_amdgcn_s_barrier();

        // ---- phase 1: B nf2-3 reads; stage (t+1).A1
        #pragma unroll
        for (int n = 2; n < 4; ++n)
            #pragma unroll
            for (int ks = 0; ks < 2; ++ks)
                bv[n][ks] = ldsfrag(lds, buf, slotB, rB + n * 16 + fr, ks, cb0);
        stage_half(lds, A, lda, brow + 128, k1, nbuf, SLOT_A1, tid);
        __builtin_amdgcn_s_barrier();
        __builtin_amdgcn_s_setprio(1);
        QUAD(0, 1)
        __builtin_amdgcn_s_setprio(0);
        __builtin_amdgcn_s_barrier();

        // ---- phase 2: A mf4-7 reads; stage (t+2).B0
        #pragma unroll
        for (int m = 0; m < 4; ++m)
            #pragma unroll
            for (int ks = 0; ks < 2; ++ks)
                af[m][ks] = ldsfrag(lds, buf, slotA, (m + 4) * 16 + fr, ks, cb0);
        stage_half(lds, B, ldb, bcol, k2, buf, SLOT_B0, tid);
        __builtin_amdgcn_s_barrier();
        __builtin_amdgcn_s_setprio(1);
        QUAD(1, 0)
        __builtin_amdgcn_s_setprio(0);
        __builtin_amdgcn_s_barrier();

        // ---- phase 3: stage (t+2).A0; counted vmcnt proves tile t+1 resident
        stage_half(lds, A, lda, brow, k2, buf, SLOT_A0, tid);
        __builtin_amdgcn_s_barrier();
        __builtin_amdgcn_s_setprio(1);
        QUAD(1, 1)
        __builtin_amdgcn_s_setprio(0);
        asm volatile("s_waitcnt vmcnt(4)" ::: "memory");
        __builtin_amdgcn_s_barrier();
    }
#undef QUAD

    // epilogue: C/D layout col = lane&15, row = (lane>>4)*4 + j
    if (MODE != 2) {
        bf16* C = Cb + (size_t)bz * sC;
        #pragma unroll
        for (int mf = 0; mf < 8; ++mf) {
            const int r0 = brow + wm * 128 + mf * 16 + fq * 4;
            #pragma unroll
            for (int nf = 0; nf < 4; ++nf) {
                const int c = bcol + wn * 64 + nf * 16 + fr;
                #pragma unroll
                for (int j = 0; j < 4; ++j)
                    C[(size_t)(r0 + j) * ldc + c] =
                        __float2bfloat16(acc[mf][nf][j] * scale);
            }
        }
    } else {
        float* C = Cf + (size_t)bz * sC;
        const bf16* R = Res + (size_t)bz * sR;
        #pragma unroll
        for (int mf = 0; mf < 8; ++mf) {
            const int r0 = brow + wm * 128 + mf * 16 + fq * 4;
            #pragma unroll
            for (int nf = 0; nf < 4; ++nf) {
                const int c = bcol + wn * 64 + nf * 16 + fr;
                #pragma unroll
                for (int j = 0; j < 4; ++j)
                    C[(size_t)(r0 + j) * ldc + c] = acc[mf][nf][j] +
                        __bfloat162float(R[(size_t)(r0 + j) * ldc + c]);
            }
        }
    }
}

// fp32 -> bf16 convert of q,k,v into stacked [3*8192][1024], 16B stores
__global__ void convert_qkv(const float* __restrict__ q, const float* __restrict__ k,
                            const float* __restrict__ v, bf16* __restrict__ Xb)
{
    const int N8 = 8192 * 1024 / 8;
    const int total = 3 * N8;
    for (int i = blockIdx.x * 256 + threadIdx.x; i < total; i += gridDim.x * 256) {
        const int t = i / N8, j = i - t * N8;
        const float4* s = (t == 0) ? (const float4*)q
                        : (t == 1) ? (const float4*)k : (const float4*)v;
        float4 a = s[2 * j], bq = s[2 * j + 1];
        float vals[8] = {a.x, a.y, a.z, a.w, bq.x, bq.y, bq.z, bq.w};
        union { short h[8]; bf16x8 v8; } o;
        #pragma unroll
        for (int e = 0; e < 8; ++e) {
            __hip_bfloat16 h = __float2bfloat16(vals[e]);
            o.h[e] = *(short*)&h;
        }
        ((bf16x8*)Xb)[i] = o.v8;
    }
}

// Wt[n][k] = bf16(wi[k][n]),  1024x1024
__global__ void transpose_wi(const float* __restrict__ wi, bf16* __restrict__ Wt)
{
    __shared__ float t[32][33];
    const int n0 = blockIdx.x * 32, k0 = blockIdx.y * 32;
    const int lx = threadIdx.x & 31, ly = threadIdx.x >> 5;
    for (int i = ly; i < 32; i += 8)
        t[i][lx] = wi[(size_t)(k0 + i) * 1024 + n0 + lx];
    __syncthreads();
    for (int i = ly; i < 32; i += 8)
        Wt[(size_t)(n0 + i) * 1024 + k0 + lx] = __float2bfloat16(t[lx][i]);
}

// vpT[b][d][s] = vp[b][s][d]
__global__ void transpose_vp(const bf16* __restrict__ vp, bf16* __restrict__ vpT)
{
    __shared__ bf16 t[32][33];
    const int b = blockIdx.z;
    const int d0 = blockIdx.x * 32, s0 = blockIdx.y * 32;
    const bf16* src = vp + (size_t)b * 2048 * 1024;
    bf16* dst = vpT + (size_t)b * 1024 * 2048;
    const int lx = threadIdx.x & 31, ly = threadIdx.x >> 5;
    for (int i = ly; i < 32; i += 8)
        t[i][lx] = src[(size_t)(s0 + i) * 1024 + d0 + lx];
    __syncthreads();
    for (int i = ly; i < 32; i += 8)
        dst[(size_t)(d0 + i) * 2048 + s0 + lx] = t[lx][i];
}

__device__ __forceinline__ float bf2f(short s) {
    union { float f; unsigned u; } c;
    c.u = ((unsigned)(unsigned short)s) << 16;
    return c.f;
}

// causal row softmax in-place on bf16 scores; zero-fill to 256-aligned boundary
__launch_bounds__(256)
__global__ void softmax_causal(bf16* __restrict__ P)
{
    const int r = blockIdx.x, b = blockIdx.y;
    bf16* row = P + ((size_t)b * 2048 + r) * 2048;
    __shared__ float sm[2048];
    __shared__ float red[8];
    const int tid = threadIdx.x;
    const int nv = r + 1;
    const int nv8 = nv & ~7;

    float lmax = -1e30f;
    for (int k = tid * 8; k < nv8; k += 2048) {
        bf16x8 x = *(const bf16x8*)(row + k);
        #pragma unroll
        for (int j = 0; j < 8; ++j) {
            float s = bf2f(x[j]);
            sm[k + j] = s;
            lmax = fmaxf(lmax, s);
        }
    }
    for (int k = nv8 + tid; k < nv; k += 256) {
        float s = __bfloat162float(row[k]);
        sm[k] = s;
        lmax = fmaxf(lmax, s);
    }
    #pragma unroll
    for (int o = 32; o; o >>= 1) lmax = fmaxf(lmax, __shfl_down(lmax, o));
    if ((tid & 63) == 0) red[tid >> 6] = lmax;
    __syncthreads();
    const float m = fmaxf(fmaxf(red[0], red[1]), fmaxf(red[2], red[3]));

    float lsum = 0.f;
    for (int k = tid; k < nv; k += 256) {
        float e = __expf(sm[k] - m);
        sm[k] = e;
        lsum += e;
    }
    #pragma unroll
    for (int o = 32; o; o >>= 1) lsum += __shfl_down(lsum, o);
    if ((tid & 63) == 0) red[4 + (tid >> 6)] = lsum;
    __syncthreads();
    const float inv = 1.0f / (red[4] + red[5] + red[6] + red[7]);

    const int rup = (r & ~255) + 256;
    for (int k = tid * 8; k < rup; k += 2048) {
        union { short s[8]; bf16x8 v; } o;
        #pragma unroll
        for (int j = 0; j < 8; ++j) {
            const int kk = k + j;
            float p = (kk < nv) ? sm[kk] * inv : 0.0f;
            __hip_bfloat16 h = __float2bfloat16(p);
            o.s[j] = *(short*)&h;
        }
        *(bf16x8*)(row + k) = o.v;
    }
}

extern "C" void kernel_launch(void* const* d_in, const int* in_sizes, int n_in,
                              void* d_out, int out_size, void* d_ws, size_t ws_size,
                              hipStream_t stream)
{
    const float* v  = (const float*)d_in[0];
    const float* k  = (const float*)d_in[1];
    const float* q  = (const float*)d_in[2];
    const float* wi = (const float*)d_in[3];
    float* out = (float*)d_out;

    char* ws = (char*)d_ws;
    const size_t WT_OFF   = 0;                       // 2 MB
    const size_t PROJ_OFF = WT_OFF + (2u << 20);     // 50.33 MB
    const size_t VPT_OFF  = PROJ_OFF + (size_t)24576 * 1024 * 2;
    const size_t XB_OFF   = VPT_OFF + (size_t)4 * 1024 * 2048 * 2;

    bf16* Wt   = (bf16*)(ws + WT_OFF);
    bf16* proj = (bf16*)(ws + PROJ_OFF);   // [q(8192)|k(8192)|v(8192)] x 1024
    bf16* vpT  = (bf16*)(ws + VPT_OFF);    // [4][1024][2048]
    bf16* Xb   = (bf16*)(ws + XB_OFF);     // [24576][1024], reused as P
    bf16* P    = Xb;                       // [4][2048][2048] aliases Xb (dead)

    bf16* qp_b = proj;
    bf16* kp_b = proj + (size_t)8192 * 1024;
    bf16* vp_b = proj + (size_t)16384 * 1024;

    const int LDSB = 131072;   // 128 KiB double-buffered tiles
    (void)hipFuncSetAttribute((const void*)gemm256<0>,
            hipFuncAttributeMaxDynamicSharedMemorySize, LDSB);
    (void)hipFuncSetAttribute((const void*)gemm256<1>,
            hipFuncAttributeMaxDynamicSharedMemorySize, LDSB);
    (void)hipFuncSetAttribute((const void*)gemm256<2>,
            hipFuncAttributeMaxDynamicSharedMemorySize, LDSB);

    convert_qkv<<<2048, 256, 0, stream>>>(q, k, v, Xb);
    transpose_wi<<<dim3(32, 32), 256, 0, stream>>>(wi, Wt);

    // projection: [24576,1024] = Xb @ Wt^T-form
    gemm256<0><<<dim3(4, 96, 1), 512, LDSB, stream>>>(
        Xb, Wt, proj, nullptr, nullptr,
        1024, 1024, 1024, 1024, 0, 0, 0, 0, 1.0f);

    transpose_vp<<<dim3(32, 64, 4), 256, 0, stream>>>(vp_b, vpT);

    // scores: per batch [2048,2048] = qp @ kp^T * 1/32, causal tile skip
    gemm256<1><<<dim3(8, 8, 4), 512, LDSB, stream>>>(
        qp_b, kp_b, P, nullptr, nullptr,
        1024, 1024, 2048, 1024,
        (long)2048 * 1024, (long)2048 * 1024, (long)2048 * 2048, 0, 0.03125f);

    softmax_causal<<<dim3(2048, 4), 256, 0, stream>>>(P);

    // out: per batch [2048,1024] = P @ vpT^T-form + qp residual, fp32
    gemm256<2><<<dim3(4, 8, 4), 512, LDSB, stream>>>(
        P, vpT, nullptr, out, qp_b,
        2048, 2048, 1024, 2048,
        (long)2048 * 2048, (long)1024 * 2048, (long)2048 * 1024, (long)2048 * 1024, 1.0f);
}

// Round 3
// 201.575 us; speedup vs baseline: 1.1112x; 1.0364x over previous
//
#include <hip/hip_runtime.h>
#include <hip/hip_bf16.h>

typedef __hip_bfloat16 bf16;
typedef short bf16x8 __attribute__((ext_vector_type(8)));
typedef float f32x4 __attribute__((ext_vector_type(4)));

#define HT 16384   // half-tile bytes: 128 rows x 64 cols bf16

__device__ __forceinline__ void gload16(const void* g, void* l) {
    __builtin_amdgcn_global_load_lds(
        (const __attribute__((address_space(1))) void*)g,
        (__attribute__((address_space(3))) void*)l, 16, 0, 0);
}

// Stage one 128x64 bf16 half-tile into LDS slot slotIdx.
// Linear LDS dest (global_load_lds rule); source pre-swizzled with the
// involution  block ^= (row&7)  so swizzled ds_reads are conflict-free.
__device__ __forceinline__ void stage_half(char* lds, const bf16* src, int ld,
                                           int rowbase, int k0, int slotIdx,
                                           int tid)
{
    char* dst = lds + (size_t)slotIdx * HT + tid * 16;
    const int sub = tid >> 3;
    const int cb  = ((tid & 7) ^ (sub & 7)) << 4;
    #pragma unroll
    for (int p = 0; p < 2; ++p) {
        const int row = p * 64 + sub;
        const char* g = (const char*)(src + (size_t)(rowbase + row) * ld + k0) + cb;
        gload16(g, dst + p * 8192);
    }
}

// read one MFMA A/B fragment (8 bf16 = 16B) with the read-side swizzle
__device__ __forceinline__ bf16x8 ldsfrag(const char* lds, int slotIdx,
                                          int row, int ks, int cb0)
{
    return *(const bf16x8*)(lds + (size_t)slotIdx * HT
                            + row * 128 + (cb0 ^ (ks << 6)));
}

// ---- fp32 A staging (projection): load early / pack+swizzled-write late ----
struct Af32 { float4 x[4]; };

__device__ __forceinline__ void loadA(const float* hsrc, int tid, Af32& r)
{
    #pragma unroll
    for (int p = 0; p < 2; ++p) {
        const int s = p * 512 + tid;
        const int row = s >> 3, gb = s & 7;
        const float4* g = (const float4*)(hsrc + (size_t)row * 1024 + gb * 8);
        r.x[p * 2]     = g[0];
        r.x[p * 2 + 1] = g[1];
    }
}

__device__ __forceinline__ void writeA(char* lds, int slotIdx, int tid,
                                       const Af32& r)
{
    #pragma unroll
    for (int p = 0; p < 2; ++p) {
        const int s = p * 512 + tid;
        const int row = s >> 3, gb = s & 7;
        const float xs[8] = {r.x[p*2].x,   r.x[p*2].y,   r.x[p*2].z,   r.x[p*2].w,
                             r.x[p*2+1].x, r.x[p*2+1].y, r.x[p*2+1].z, r.x[p*2+1].w};
        union { short h[8]; bf16x8 v8; } o;
        #pragma unroll
        for (int e = 0; e < 8; ++e) {
            bf16 hh = __float2bfloat16(xs[e]);
            o.h[e] = *(short*)&hh;
        }
        *(bf16x8*)(lds + (size_t)slotIdx * HT + row * 128
                   + ((gb ^ (row & 7)) << 4)) = o.v8;
    }
}

// ============ projection: [24576,1024] = [q;k;v]_f32 @ Wt^T-form ============
// 256x256 tile, BK=64, 8 waves 2Mx4N. Slots/buf: A0=0 A1=1 B0=2 B1=3 (128 KiB).
__launch_bounds__(512, 2)
__global__ void proj_gemm(const float* __restrict__ q, const float* __restrict__ k,
                          const float* __restrict__ v, const bf16* __restrict__ B,
                          bf16* __restrict__ C)
{
    extern __shared__ char lds[];
    const int gx = gridDim.x;
    int id = blockIdx.y * gx + blockIdx.x;
    const int chunk = (gridDim.y * gx) >> 3;
    id = (id & 7) * chunk + (id >> 3);
    const int bj = id % gx, bi = id / gx;
    const int brow = bi * 256, bcol = bj * 256;
    const float* Asrc = (bi < 32) ? q : (bi < 64) ? k : v;
    const int lrow = (bi & 31) * 256;

    const int tid  = threadIdx.x;
    const int lane = tid & 63;
    const int w    = tid >> 6;
    const int wm   = w >> 2, wn = w & 3;
    const int fr   = lane & 15, fq = lane >> 4;
    const int cb0  = ((fr & 7) ^ fq) << 4;
    const int slotA = wm;              // A half this wave reads
    const int slotB = 2 + (wn >> 1);
    const int rB    = (wn & 1) * 64;
    const int NT = 16;                 // K=1024 / 64

    f32x4 acc[8][4] = {};
    bf16x8 af[4][2], bv[4][2];
    Af32 ar;

    // prologue: tile0 {B0,B1,A0,A1} + tile1 {B0}
    stage_half(lds, B, 1024, bcol,       0,  2, tid);
    stage_half(lds, B, 1024, bcol + 128, 0,  3, tid);
    stage_half(lds, B, 1024, bcol,      64,  6, tid);
    loadA(Asrc + (size_t)lrow * 1024, tid, ar);
    writeA(lds, 0, tid, ar);
    loadA(Asrc + (size_t)(lrow + 128) * 1024, tid, ar);
    writeA(lds, 1, tid, ar);
    asm volatile("s_waitcnt lgkmcnt(0)" ::: "memory");
    asm volatile("s_waitcnt vmcnt(2)" ::: "memory");
    __builtin_amdgcn_s_barrier();

#define QUAD(mh, nh)                                                          \
    _Pragma("unroll") for (int m = 0; m < 4; ++m)                             \
    _Pragma("unroll") for (int n = 0; n < 2; ++n)                             \
    _Pragma("unroll") for (int ks = 0; ks < 2; ++ks)                          \
        acc[(mh)*4+m][(nh)*2+n] = __builtin_amdgcn_mfma_f32_16x16x32_bf16(    \
            af[m][ks], bv[(nh)*2+n][ks], acc[(mh)*4+m][(nh)*2+n], 0, 0, 0);

    for (int t = 0; t < NT; ++t) {
        const int buf = t & 1, nbuf = buf ^ 1;
        const int k1 = min(t + 1, NT - 1) << 6;
        const int k2 = min(t + 2, NT - 1) << 6;

        // ph0: reads A mf0-3 + B nf0-1; issue A0(t+1) f32 loads; stage (t+1).B1
        #pragma unroll
        for (int m = 0; m < 4; ++m)
            #pragma unroll
            for (int ks = 0; ks < 2; ++ks)
                af[m][ks] = ldsfrag(lds, buf * 4 + slotA, m * 16 + fr, ks, cb0);
        #pragma unroll
        for (int n = 0; n < 2; ++n)
            #pragma unroll
            for (int ks = 0; ks < 2; ++ks)
                bv[n][ks] = ldsfrag(lds, buf * 4 + slotB, rB + n * 16 + fr, ks, cb0);
        loadA(Asrc + (size_t)lrow * 1024 + k1, tid, ar);
        stage_half(lds, B, 1024, bcol + 128, k1, nbuf * 4 + 3, tid);
        __builtin_amdgcn_s_barrier();
        __builtin_amdgcn_s_setprio(1);
        QUAD(0, 0)
        __builtin_amdgcn_s_setprio(0);
        __builtin_amdgcn_s_barrier();

        // ph1: reads B nf2-3; pack+write A0(t+1)
        #pragma unroll
        for (int n = 2; n < 4; ++n)
            #pragma unroll
            for (int ks = 0; ks < 2; ++ks)
                bv[n][ks] = ldsfrag(lds, buf * 4 + slotB, rB + n * 16 + fr, ks, cb0);
        writeA(lds, nbuf * 4 + 0, tid, ar);
        asm volatile("s_waitcnt lgkmcnt(0)" ::: "memory");
        __builtin_amdgcn_s_barrier();
        __builtin_amdgcn_s_setprio(1);
        QUAD(0, 1)
        __builtin_amdgcn_s_setprio(0);
        __builtin_amdgcn_s_barrier();

        // ph2: reads A mf4-7; issue A1(t+1) f32 loads; stage (t+2).B0
        #pragma unroll
        for (int m = 0; m < 4; ++m)
            #pragma unroll
            for (int ks = 0; ks < 2; ++ks)
                af[m][ks] = ldsfrag(lds, buf * 4 + slotA, (m + 4) * 16 + fr, ks, cb0);
        loadA(Asrc + (size_t)(lrow + 128) * 1024 + k1, tid, ar);
        stage_half(lds, B, 1024, bcol, k2, buf * 4 + 2, tid);
        __builtin_amdgcn_s_barrier();
        __builtin_amdgcn_s_setprio(1);
        QUAD(1, 0)
        __builtin_amdgcn_s_setprio(0);
        __builtin_amdgcn_s_barrier();

        // ph3: pack+write A1(t+1); counted vmcnt keeps (t+2).B0 in flight
        writeA(lds, nbuf * 4 + 1, tid, ar);
        asm volatile("s_waitcnt lgkmcnt(0)" ::: "memory");
        __builtin_amdgcn_s_setprio(1);
        QUAD(1, 1)
        __builtin_amdgcn_s_setprio(0);
        asm volatile("s_waitcnt vmcnt(2)" ::: "memory");
        __builtin_amdgcn_s_barrier();
    }
#undef QUAD

    #pragma unroll
    for (int mf = 0; mf < 8; ++mf) {
        const int r0 = brow + wm * 128 + mf * 16 + fq * 4;
        #pragma unroll
        for (int nf = 0; nf < 4; ++nf) {
            const int c = bcol + wn * 64 + nf * 16 + fr;
            #pragma unroll
            for (int j = 0; j < 4; ++j)
                C[(size_t)(r0 + j) * 1024 + c] = __float2bfloat16(acc[mf][nf][j]);
        }
    }
}

// ====== BM=256 x BN=128 GEMM: MODE 1 = scores (causal), MODE 2 = PV ======
// Slots/buf: A0=0 A1=1 B=2 (96 KiB total). 8 waves 4Mx2N, wave tile 64x64.
template<int MODE>
__launch_bounds__(512, 2)
__global__ void gemm_bn128(const bf16* __restrict__ A, const bf16* __restrict__ B,
                           bf16* __restrict__ Cb, float* __restrict__ Cf,
                           const bf16* __restrict__ Res,
                           int lda, int ldb, int ldc, int K,
                           long sA, long sB, long sC, long sR, float scale)
{
    extern __shared__ char lds[];
    int bi, bj;
    if (MODE == 1) { bj = blockIdx.x; bi = blockIdx.y; if (bj > 2 * bi + 1) return; }
    else           { bi = blockIdx.x; bj = blockIdx.y; }
    const int bz = blockIdx.z;
    A += (size_t)bz * sA;
    B += (size_t)bz * sB;
    const int brow = bi * 256, bcol = bj * 128;

    const int tid  = threadIdx.x;
    const int lane = tid & 63;
    const int w    = tid >> 6;
    const int wm   = w >> 1, wn = w & 1;
    const int fr   = lane & 15, fq = lane >> 4;
    const int cb0  = ((fr & 7) ^ fq) << 4;
    const int slotA = wm >> 1;
    const int rA    = (wm & 1) * 64;
    const int rB    = wn * 64;

    const int kmax = (MODE == 2) ? (brow + 256) : K;
    const int NT   = kmax >> 6;     // 4..32

    f32x4 acc[4][4] = {};
    bf16x8 af[4][2], bv[4][2];

    // prologue: tile0 {B,A0,A1} + tile1 {B}
    stage_half(lds, B, ldb, bcol,       0, 2, tid);
    stage_half(lds, A, lda, brow,       0, 0, tid);
    stage_half(lds, A, lda, brow + 128, 0, 1, tid);
    stage_half(lds, B, ldb, bcol,      64, 5, tid);
    asm volatile("s_waitcnt vmcnt(2)" ::: "memory");
    __builtin_amdgcn_s_barrier();

#define QUAD2(m0, n0)                                                         \
    _Pragma("unroll") for (int dm = 0; dm < 2; ++dm)                          \
    _Pragma("unroll") for (int dn = 0; dn < 2; ++dn)                          \
    _Pragma("unroll") for (int ks = 0; ks < 2; ++ks)                          \
        acc[(m0)+dm][(n0)+dn] = __builtin_amdgcn_mfma_f32_16x16x32_bf16(      \
            af[(m0)+dm][ks], bv[(n0)+dn][ks], acc[(m0)+dm][(n0)+dn], 0, 0, 0);

    for (int t = 0; t < NT; ++t) {
        const int buf = t & 1, nbuf = buf ^ 1;
        const int k1 = min(t + 1, NT - 1) << 6;
        const int k2 = min(t + 2, NT - 1) << 6;

        // ph0: read af01 + bv01; stage (t+1).A0
        #pragma unroll
        for (int m = 0; m < 2; ++m)
            #pragma unroll
            for (int ks = 0; ks < 2; ++ks)
                af[m][ks] = ldsfrag(lds, buf * 3 + slotA, rA + m * 16 + fr, ks, cb0);
        #pragma unroll
        for (int n = 0; n < 2; ++n)
            #pragma unroll
            for (int ks = 0; ks < 2; ++ks)
                bv[n][ks] = ldsfrag(lds, buf * 3 + 2, rB + n * 16 + fr, ks, cb0);
        stage_half(lds, A, lda, brow, k1, nbuf * 3 + 0, tid);
        __builtin_amdgcn_s_barrier();
        __builtin_amdgcn_s_setprio(1);
        QUAD2(0, 0)
        __builtin_amdgcn_s_setprio(0);
        __builtin_amdgcn_s_barrier();

        // ph1: read bv23; stage (t+1).A1
        #pragma unroll
        for (int n = 2; n < 4; ++n)
            #pragma unroll
            for (int ks = 0; ks < 2; ++ks)
                bv[n][ks] = ldsfrag(lds, buf * 3 + 2, rB + n * 16 + fr, ks, cb0);
        stage_half(lds, A, lda, brow + 128, k1, nbuf * 3 + 1, tid);
        __builtin_amdgcn_s_barrier();
        __builtin_amdgcn_s_setprio(1);
        QUAD2(0, 2)
        __builtin_amdgcn_s_setprio(0);
        __builtin_amdgcn_s_barrier();

        // ph2: read af23; stage (t+2).B
        #pragma unroll
        for (int m = 2; m < 4; ++m)
            #pragma unroll
            for (int ks = 0; ks < 2; ++ks)
                af[m][ks] = ldsfrag(lds, buf * 3 + slotA, rA + m * 16 + fr, ks, cb0);
        stage_half(lds, B, ldb, bcol, k2, buf * 3 + 2, tid);
        __builtin_amdgcn_s_barrier();
        __builtin_amdgcn_s_setprio(1);
        QUAD2(2, 2)
        __builtin_amdgcn_s_setprio(0);
        __builtin_amdgcn_s_barrier();

        // ph3: remaining quadrant; counted vmcnt leaves (t+2).B in flight
        __builtin_amdgcn_s_setprio(1);
        QUAD2(2, 0)
        __builtin_amdgcn_s_setprio(0);
        asm volatile("s_waitcnt vmcnt(2)" ::: "memory");
        __builtin_amdgcn_s_barrier();
    }
#undef QUAD2

    if (MODE == 1) {
        bf16* C = Cb + (size_t)bz * sC;
        #pragma unroll
        for (int mf = 0; mf < 4; ++mf) {
            const int r0 = brow + wm * 64 + mf * 16 + fq * 4;
            #pragma unroll
            for (int nf = 0; nf < 4; ++nf) {
                const int c = bcol + wn * 64 + nf * 16 + fr;
                #pragma unroll
                for (int j = 0; j < 4; ++j)
                    C[(size_t)(r0 + j) * ldc + c] =
                        __float2bfloat16(acc[mf][nf][j] * scale);
            }
        }
    } else {
        float* C = Cf + (size_t)bz * sC;
        const bf16* R = Res + (size_t)bz * sR;
        #pragma unroll
        for (int mf = 0; mf < 4; ++mf) {
            const int r0 = brow + wm * 64 + mf * 16 + fq * 4;
            #pragma unroll
            for (int nf = 0; nf < 4; ++nf) {
                const int c = bcol + wn * 64 + nf * 16 + fr;
                #pragma unroll
                for (int j = 0; j < 4; ++j)
                    C[(size_t)(r0 + j) * ldc + c] = acc[mf][nf][j] +
                        __bfloat162float(R[(size_t)(r0 + j) * ldc + c]);
            }
        }
    }
}

// Wt[n][k] = bf16(wi[k][n]),  1024x1024
__global__ void transpose_wi(const float* __restrict__ wi, bf16* __restrict__ Wt)
{
    __shared__ float t[32][33];
    const int n0 = blockIdx.x * 32, k0 = blockIdx.y * 32;
    const int lx = threadIdx.x & 31, ly = threadIdx.x >> 5;
    for (int i = ly; i < 32; i += 8)
        t[i][lx] = wi[(size_t)(k0 + i) * 1024 + n0 + lx];
    __syncthreads();
    for (int i = ly; i < 32; i += 8)
        Wt[(size_t)(n0 + i) * 1024 + k0 + lx] = __float2bfloat16(t[lx][i]);
}

// vpT[b][d][s] = vp[b][s][d]
__global__ void transpose_vp(const bf16* __restrict__ vp, bf16* __restrict__ vpT)
{
    __shared__ bf16 t[32][33];
    const int b = blockIdx.z;
    const int d0 = blockIdx.x * 32, s0 = blockIdx.y * 32;
    const bf16* src = vp + (size_t)b * 2048 * 1024;
    bf16* dst = vpT + (size_t)b * 1024 * 2048;
    const int lx = threadIdx.x & 31, ly = threadIdx.x >> 5;
    for (int i = ly; i < 32; i += 8)
        t[i][lx] = src[(size_t)(s0 + i) * 1024 + d0 + lx];
    __syncthreads();
    for (int i = ly; i < 32; i += 8)
        dst[(size_t)(d0 + i) * 2048 + s0 + lx] = t[lx][i];
}

__device__ __forceinline__ float bf2f(short s) {
    union { float f; unsigned u; } c;
    c.u = ((unsigned)(unsigned short)s) << 16;
    return c.f;
}

// wave-per-row causal softmax, in-register; zero-fill to 256-aligned boundary
__launch_bounds__(256)
__global__ void softmax_rows(bf16* __restrict__ P)
{
    const int wid = threadIdx.x >> 6, lane = threadIdx.x & 63;
    const int r = blockIdx.x * 4 + wid, b = blockIdx.y;
    bf16* row = P + ((size_t)b * 2048 + r) * 2048;
    const int nv  = r + 1;
    const int rup = (r & ~255) + 256;

    float vals[4][8];
    float m = -1e30f;
    #pragma unroll
    for (int c = 0; c < 4; ++c) {
        const int k0 = c * 512 + lane * 8;
        bf16x8 x = *(const bf16x8*)(row + k0);
        #pragma unroll
        for (int j = 0; j < 8; ++j) {
            float f = (k0 + j < nv) ? bf2f(x[j]) : -1e30f;
            vals[c][j] = f;
            m = fmaxf(m, f);
        }
    }
    #pragma unroll
    for (int o = 32; o; o >>= 1) m = fmaxf(m, __shfl_xor(m, o));

    float sum = 0.f;
    #pragma unroll
    for (int c = 0; c < 4; ++c)
        #pragma unroll
        for (int j = 0; j < 8; ++j) {
            float e = __expf(vals[c][j] - m);   // masked -> exp(-huge) = 0
            vals[c][j] = e;
            sum += e;
        }
    #pragma unroll
    for (int o = 32; o; o >>= 1) sum += __shfl_xor(sum, o);
    const float inv = 1.0f / sum;

    #pragma unroll
    for (int c = 0; c < 4; ++c) {
        const int k0 = c * 512 + lane * 8;
        if (k0 < rup) {
            union { short h[8]; bf16x8 v8; } o;
            #pragma unroll
            for (int j = 0; j < 8; ++j) {
                bf16 hh = __float2bfloat16(vals[c][j] * inv);
                o.h[j] = *(short*)&hh;
            }
            *(bf16x8*)(row + k0) = o.v8;
        }
    }
}

extern "C" void kernel_launch(void* const* d_in, const int* in_sizes, int n_in,
                              void* d_out, int out_size, void* d_ws, size_t ws_size,
                              hipStream_t stream)
{
    const float* v  = (const float*)d_in[0];
    const float* k  = (const float*)d_in[1];
    const float* q  = (const float*)d_in[2];
    const float* wi = (const float*)d_in[3];
    float* out = (float*)d_out;

    char* ws = (char*)d_ws;
    const size_t WT_OFF   = 0;                       // 2 MB
    const size_t PROJ_OFF = WT_OFF + (2u << 20);     // 48 MB
    const size_t VPT_OFF  = PROJ_OFF + (size_t)24576 * 1024 * 2;   // 16 MB
    const size_t P_OFF    = VPT_OFF + (size_t)4 * 1024 * 2048 * 2; // 32 MB

    bf16* Wt   = (bf16*)(ws + WT_OFF);
    bf16* proj = (bf16*)(ws + PROJ_OFF);   // [q(8192)|k(8192)|v(8192)] x 1024
    bf16* vpT  = (bf16*)(ws + VPT_OFF);    // [4][1024][2048]
    bf16* P    = (bf16*)(ws + P_OFF);      // [4][2048][2048]

    bf16* qp_b = proj;
    bf16* kp_b = proj + (size_t)8192 * 1024;
    bf16* vp_b = proj + (size_t)16384 * 1024;

    (void)hipFuncSetAttribute((const void*)proj_gemm,
            hipFuncAttributeMaxDynamicSharedMemorySize, 131072);
    (void)hipFuncSetAttribute((const void*)gemm_bn128<1>,
            hipFuncAttributeMaxDynamicSharedMemorySize, 98304);
    (void)hipFuncSetAttribute((const void*)gemm_bn128<2>,
            hipFuncAttributeMaxDynamicSharedMemorySize, 98304);

    transpose_wi<<<dim3(32, 32), 256, 0, stream>>>(wi, Wt);

    // projection (reads f32 q,k,v directly; fused convert)
    proj_gemm<<<dim3(4, 96), 512, 131072, stream>>>(q, k, v, Wt, proj);

    transpose_vp<<<dim3(32, 64, 4), 256, 0, stream>>>(vp_b, vpT);

    // scores: per batch [2048,2048] = qp @ kp^T * 1/32, causal skip (128-col tiles)
    gemm_bn128<1><<<dim3(16, 8, 4), 512, 98304, stream>>>(
        qp_b, kp_b, P, nullptr, nullptr,
        1024, 1024, 2048, 1024,
        (long)2048 * 1024, (long)2048 * 1024, (long)2048 * 2048, 0, 0.03125f);

    softmax_rows<<<dim3(512, 4), 256, 0, stream>>>(P);

    // PV: per batch [2048,1024] = P @ vpT^T-form + qp residual (f32 out)
    // blockIdx.x = bi so each XCD keeps one P row-panel resident in its L2
    gemm_bn128<2><<<dim3(8, 8, 4), 512, 98304, stream>>>(
        P, vpT, nullptr, out, qp_b,
        2048, 2048, 1024, 2048,
        (long)2048 * 2048, (long)1024 * 2048, (long)2048 * 1024, (long)2048 * 1024, 1.0f);
}

// Round 4
// 191.946 us; speedup vs baseline: 1.1670x; 1.0502x over previous
//
#include <hip/hip_runtime.h>
#include <hip/hip_bf16.h>

typedef __hip_bfloat16 bf16;
typedef short bf16x8 __attribute__((ext_vector_type(8)));
typedef float f32x4 __attribute__((ext_vector_type(4)));

#define HT 16384   // half-tile bytes: 128 rows x 64 cols bf16

__device__ __forceinline__ void gload16(const void* g, void* l) {
    __builtin_amdgcn_global_load_lds(
        (const __attribute__((address_space(1))) void*)g,
        (__attribute__((address_space(3))) void*)l, 16, 0, 0);
}

// Stage one 128x64 bf16 half-tile into LDS slot slotIdx.
// Linear LDS dest (global_load_lds rule); source pre-swizzled with the
// involution  block ^= (row&7)  so swizzled ds_reads are conflict-free.
__device__ __forceinline__ void stage_half(char* lds, const bf16* src, int ld,
                                           int rowbase, int k0, int slotIdx,
                                           int tid)
{
    char* dst = lds + (size_t)slotIdx * HT + tid * 16;
    const int sub = tid >> 3;
    const int cb  = ((tid & 7) ^ (sub & 7)) << 4;
    #pragma unroll
    for (int p = 0; p < 2; ++p) {
        const int row = p * 64 + sub;
        const char* g = (const char*)(src + (size_t)(rowbase + row) * ld + k0) + cb;
        gload16(g, dst + p * 8192);
    }
}

// read one MFMA A/B fragment (8 bf16 = 16B) with the read-side swizzle
__device__ __forceinline__ bf16x8 ldsfrag(const char* lds, int slotIdx,
                                          int row, int ks, int cb0)
{
    return *(const bf16x8*)(lds + (size_t)slotIdx * HT
                            + row * 128 + (cb0 ^ (ks << 6)));
}

// ===== projection: [24576,1024] bf16 = Xb @ Wt^T-form, 256x256 tile =====
// 8 waves 2Mx4N, BK=64, dbuf slots A0=0 A1=1 B0=2 B1=3 (128 KiB), vmcnt(4).
__launch_bounds__(512, 2)
__global__ void proj_gemm256(const bf16* __restrict__ A, const bf16* __restrict__ B,
                             bf16* __restrict__ C)
{
    extern __shared__ char lds[];
    const int gx = gridDim.x;
    int id = blockIdx.y * gx + blockIdx.x;
    const int chunk = (gridDim.y * gx) >> 3;
    id = (id & 7) * chunk + (id >> 3);
    const int bj = id % gx, bi = id / gx;
    const int brow = bi * 256, bcol = bj * 256;

    const int tid  = threadIdx.x;
    const int lane = tid & 63;
    const int w    = tid >> 6;
    const int wm   = w >> 2, wn = w & 3;
    const int fr   = lane & 15, fq = lane >> 4;
    const int cb0  = ((fr & 7) ^ fq) << 4;
    const int slotA = wm;
    const int slotB = 2 + (wn >> 1);
    const int rB    = (wn & 1) * 64;
    const int NT    = 16;   // K=1024 / 64

    f32x4 acc[8][4] = {};
    bf16x8 af[4][2], bv[4][2];

    // prologue: tile0 {B0,A0,B1,A1} + tile1 {B0,A0}; leave 4 in flight
    stage_half(lds, B, 1024, bcol,       0, 2, tid);
    stage_half(lds, A, 1024, brow,       0, 0, tid);
    stage_half(lds, B, 1024, bcol + 128, 0, 3, tid);
    stage_half(lds, A, 1024, brow + 128, 0, 1, tid);
    stage_half(lds, B, 1024, bcol,      64, 6, tid);
    stage_half(lds, A, 1024, brow,      64, 4, tid);
    asm volatile("s_waitcnt vmcnt(4)" ::: "memory");
    __builtin_amdgcn_s_barrier();

#define QUAD(mh, nh)                                                          \
    _Pragma("unroll") for (int m = 0; m < 4; ++m)                             \
    _Pragma("unroll") for (int n = 0; n < 2; ++n)                             \
    _Pragma("unroll") for (int ks = 0; ks < 2; ++ks)                          \
        acc[(mh)*4+m][(nh)*2+n] = __builtin_amdgcn_mfma_f32_16x16x32_bf16(    \
            af[m][ks], bv[(nh)*2+n][ks], acc[(mh)*4+m][(nh)*2+n], 0, 0, 0);

    for (int t = 0; t < NT; ++t) {
        const int buf = t & 1, nbuf = buf ^ 1;
        const int k1 = min(t + 1, NT - 1) << 6;
        const int k2 = min(t + 2, NT - 1) << 6;

        // ph0: read A mf0-3 + B nf0-1; stage (t+1).B1
        #pragma unroll
        for (int m = 0; m < 4; ++m)
            #pragma unroll
            for (int ks = 0; ks < 2; ++ks)
                af[m][ks] = ldsfrag(lds, buf * 4 + slotA, m * 16 + fr, ks, cb0);
        #pragma unroll
        for (int n = 0; n < 2; ++n)
            #pragma unroll
            for (int ks = 0; ks < 2; ++ks)
                bv[n][ks] = ldsfrag(lds, buf * 4 + slotB, rB + n * 16 + fr, ks, cb0);
        stage_half(lds, B, 1024, bcol + 128, k1, nbuf * 4 + 3, tid);
        __builtin_amdgcn_s_barrier();
        __builtin_amdgcn_s_setprio(1);
        QUAD(0, 0)
        __builtin_amdgcn_s_setprio(0);
        __builtin_amdgcn_s_barrier();

        // ph1: read B nf2-3; stage (t+1).A1
        #pragma unroll
        for (int n = 2; n < 4; ++n)
            #pragma unroll
            for (int ks = 0; ks < 2; ++ks)
                bv[n][ks] = ldsfrag(lds, buf * 4 + slotB, rB + n * 16 + fr, ks, cb0);
        stage_half(lds, A, 1024, brow + 128, k1, nbuf * 4 + 1, tid);
        __builtin_amdgcn_s_barrier();
        __builtin_amdgcn_s_setprio(1);
        QUAD(0, 1)
        __builtin_amdgcn_s_setprio(0);
        __builtin_amdgcn_s_barrier();

        // ph2: read A mf4-7; stage (t+2).B0
        #pragma unroll
        for (int m = 0; m < 4; ++m)
            #pragma unroll
            for (int ks = 0; ks < 2; ++ks)
                af[m][ks] = ldsfrag(lds, buf * 4 + slotA, (m + 4) * 16 + fr, ks, cb0);
        stage_half(lds, B, 1024, bcol, k2, buf * 4 + 2, tid);
        __builtin_amdgcn_s_barrier();
        __builtin_amdgcn_s_setprio(1);
        QUAD(1, 0)
        __builtin_amdgcn_s_setprio(0);
        __builtin_amdgcn_s_barrier();

        // ph3: stage (t+2).A0; counted vmcnt proves tile t+1 resident
        stage_half(lds, A, 1024, brow, k2, buf * 4 + 0, tid);
        __builtin_amdgcn_s_barrier();
        __builtin_amdgcn_s_setprio(1);
        QUAD(1, 1)
        __builtin_amdgcn_s_setprio(0);
        asm volatile("s_waitcnt vmcnt(4)" ::: "memory");
        __builtin_amdgcn_s_barrier();
    }
#undef QUAD

    #pragma unroll
    for (int mf = 0; mf < 8; ++mf) {
        const int r0 = brow + wm * 128 + mf * 16 + fq * 4;
        #pragma unroll
        for (int nf = 0; nf < 4; ++nf) {
            const int c = bcol + wn * 64 + nf * 16 + fr;
            #pragma unroll
            for (int j = 0; j < 4; ++j)
                C[(size_t)(r0 + j) * 1024 + c] = __float2bfloat16(acc[mf][nf][j]);
        }
    }
}

// ====== BM=256 x BN=128 GEMM: MODE 1 = scores (causal), MODE 2 = PV ======
// Slots/buf: A0=0 A1=1 B=2 (96 KiB total). 8 waves 4Mx2N, wave tile 64x64.
template<int MODE>
__launch_bounds__(512, 2)
__global__ void gemm_bn128(const bf16* __restrict__ A, const bf16* __restrict__ B,
                           bf16* __restrict__ Cb, float* __restrict__ Cf,
                           const bf16* __restrict__ Res,
                           int lda, int ldb, int ldc, int K,
                           long sA, long sB, long sC, long sR, float scale)
{
    extern __shared__ char lds[];
    int bi, bj;
    if (MODE == 1) { bj = blockIdx.x; bi = blockIdx.y; if (bj > 2 * bi + 1) return; }
    else           { bi = blockIdx.x; bj = blockIdx.y; }
    const int bz = blockIdx.z;
    A += (size_t)bz * sA;
    B += (size_t)bz * sB;
    const int brow = bi * 256, bcol = bj * 128;

    const int tid  = threadIdx.x;
    const int lane = tid & 63;
    const int w    = tid >> 6;
    const int wm   = w >> 1, wn = w & 1;
    const int fr   = lane & 15, fq = lane >> 4;
    const int cb0  = ((fr & 7) ^ fq) << 4;
    const int slotA = wm >> 1;
    const int rA    = (wm & 1) * 64;
    const int rB    = wn * 64;

    const int kmax = (MODE == 2) ? (brow + 256) : K;
    const int NT   = kmax >> 6;     // 4..32

    f32x4 acc[4][4] = {};
    bf16x8 af[4][2], bv[4][2];

    // prologue: tile0 {B,A0,A1} + tile1 {B}
    stage_half(lds, B, ldb, bcol,       0, 2, tid);
    stage_half(lds, A, lda, brow,       0, 0, tid);
    stage_half(lds, A, lda, brow + 128, 0, 1, tid);
    stage_half(lds, B, ldb, bcol,      64, 5, tid);
    asm volatile("s_waitcnt vmcnt(2)" ::: "memory");
    __builtin_amdgcn_s_barrier();

#define QUAD2(m0, n0)                                                         \
    _Pragma("unroll") for (int dm = 0; dm < 2; ++dm)                          \
    _Pragma("unroll") for (int dn = 0; dn < 2; ++dn)                          \
    _Pragma("unroll") for (int ks = 0; ks < 2; ++ks)                          \
        acc[(m0)+dm][(n0)+dn] = __builtin_amdgcn_mfma_f32_16x16x32_bf16(      \
            af[(m0)+dm][ks], bv[(n0)+dn][ks], acc[(m0)+dm][(n0)+dn], 0, 0, 0);

    for (int t = 0; t < NT; ++t) {
        const int buf = t & 1, nbuf = buf ^ 1;
        const int k1 = min(t + 1, NT - 1) << 6;
        const int k2 = min(t + 2, NT - 1) << 6;

        // ph0: read af01 + bv01; stage (t+1).A0
        #pragma unroll
        for (int m = 0; m < 2; ++m)
            #pragma unroll
            for (int ks = 0; ks < 2; ++ks)
                af[m][ks] = ldsfrag(lds, buf * 3 + slotA, rA + m * 16 + fr, ks, cb0);
        #pragma unroll
        for (int n = 0; n < 2; ++n)
            #pragma unroll
            for (int ks = 0; ks < 2; ++ks)
                bv[n][ks] = ldsfrag(lds, buf * 3 + 2, rB + n * 16 + fr, ks, cb0);
        stage_half(lds, A, lda, brow, k1, nbuf * 3 + 0, tid);
        __builtin_amdgcn_s_barrier();
        __builtin_amdgcn_s_setprio(1);
        QUAD2(0, 0)
        __builtin_amdgcn_s_setprio(0);
        __builtin_amdgcn_s_barrier();

        // ph1: read bv23; stage (t+1).A1
        #pragma unroll
        for (int n = 2; n < 4; ++n)
            #pragma unroll
            for (int ks = 0; ks < 2; ++ks)
                bv[n][ks] = ldsfrag(lds, buf * 3 + 2, rB + n * 16 + fr, ks, cb0);
        stage_half(lds, A, lda, brow + 128, k1, nbuf * 3 + 1, tid);
        __builtin_amdgcn_s_barrier();
        __builtin_amdgcn_s_setprio(1);
        QUAD2(0, 2)
        __builtin_amdgcn_s_setprio(0);
        __builtin_amdgcn_s_barrier();

        // ph2: read af23; stage (t+2).B
        #pragma unroll
        for (int m = 2; m < 4; ++m)
            #pragma unroll
            for (int ks = 0; ks < 2; ++ks)
                af[m][ks] = ldsfrag(lds, buf * 3 + slotA, rA + m * 16 + fr, ks, cb0);
        stage_half(lds, B, ldb, bcol, k2, buf * 3 + 2, tid);
        __builtin_amdgcn_s_barrier();
        __builtin_amdgcn_s_setprio(1);
        QUAD2(2, 2)
        __builtin_amdgcn_s_setprio(0);
        __builtin_amdgcn_s_barrier();

        // ph3: remaining quadrant; counted vmcnt leaves (t+2).B in flight
        __builtin_amdgcn_s_setprio(1);
        QUAD2(2, 0)
        __builtin_amdgcn_s_setprio(0);
        asm volatile("s_waitcnt vmcnt(2)" ::: "memory");
        __builtin_amdgcn_s_barrier();
    }
#undef QUAD2

    if (MODE == 1) {
        bf16* C = Cb + (size_t)bz * sC;
        #pragma unroll
        for (int mf = 0; mf < 4; ++mf) {
            const int r0 = brow + wm * 64 + mf * 16 + fq * 4;
            #pragma unroll
            for (int nf = 0; nf < 4; ++nf) {
                const int c = bcol + wn * 64 + nf * 16 + fr;
                #pragma unroll
                for (int j = 0; j < 4; ++j)
                    C[(size_t)(r0 + j) * ldc + c] =
                        __float2bfloat16(acc[mf][nf][j] * scale);
            }
        }
    } else {
        float* C = Cf + (size_t)bz * sC;
        const bf16* R = Res + (size_t)bz * sR;
        #pragma unroll
        for (int mf = 0; mf < 4; ++mf) {
            const int r0 = brow + wm * 64 + mf * 16 + fq * 4;
            #pragma unroll
            for (int nf = 0; nf < 4; ++nf) {
                const int c = bcol + wn * 64 + nf * 16 + fr;
                #pragma unroll
                for (int j = 0; j < 4; ++j)
                    C[(size_t)(r0 + j) * ldc + c] = acc[mf][nf][j] +
                        __bfloat162float(R[(size_t)(r0 + j) * ldc + c]);
            }
        }
    }
}

// fp32 -> bf16 convert of q,k,v into stacked [3*8192][1024], 16B stores
__global__ void convert_qkv(const float* __restrict__ q, const float* __restrict__ k,
                            const float* __restrict__ v, bf16* __restrict__ Xb)
{
    const int N8 = 8192 * 1024 / 8;
    const int total = 3 * N8;
    for (int i = blockIdx.x * 256 + threadIdx.x; i < total; i += gridDim.x * 256) {
        const int t = i / N8, j = i - t * N8;
        const float4* s = (t == 0) ? (const float4*)q
                        : (t == 1) ? (const float4*)k : (const float4*)v;
        float4 a = s[2 * j], bq = s[2 * j + 1];
        float vals[8] = {a.x, a.y, a.z, a.w, bq.x, bq.y, bq.z, bq.w};
        union { short h[8]; bf16x8 v8; } o;
        #pragma unroll
        for (int e = 0; e < 8; ++e) {
            bf16 hh = __float2bfloat16(vals[e]);
            o.h[e] = *(short*)&hh;
        }
        ((bf16x8*)Xb)[i] = o.v8;
    }
}

// Wt[n][k] = bf16(wi[k][n]),  1024x1024
__global__ void transpose_wi(const float* __restrict__ wi, bf16* __restrict__ Wt)
{
    __shared__ float t[32][33];
    const int n0 = blockIdx.x * 32, k0 = blockIdx.y * 32;
    const int lx = threadIdx.x & 31, ly = threadIdx.x >> 5;
    for (int i = ly; i < 32; i += 8)
        t[i][lx] = wi[(size_t)(k0 + i) * 1024 + n0 + lx];
    __syncthreads();
    for (int i = ly; i < 32; i += 8)
        Wt[(size_t)(n0 + i) * 1024 + k0 + lx] = __float2bfloat16(t[lx][i]);
}

// vpT[b][d][s] = vp[b][s][d]
__global__ void transpose_vp(const bf16* __restrict__ vp, bf16* __restrict__ vpT)
{
    __shared__ bf16 t[32][33];
    const int b = blockIdx.z;
    const int d0 = blockIdx.x * 32, s0 = blockIdx.y * 32;
    const bf16* src = vp + (size_t)b * 2048 * 1024;
    bf16* dst = vpT + (size_t)b * 1024 * 2048;
    const int lx = threadIdx.x & 31, ly = threadIdx.x >> 5;
    for (int i = ly; i < 32; i += 8)
        t[i][lx] = src[(size_t)(s0 + i) * 1024 + d0 + lx];
    __syncthreads();
    for (int i = ly; i < 32; i += 8)
        dst[(size_t)(d0 + i) * 2048 + s0 + lx] = t[lx][i];
}

__device__ __forceinline__ float bf2f(short s) {
    union { float f; unsigned u; } c;
    c.u = ((unsigned)(unsigned short)s) << 16;
    return c.f;
}

// wave-per-row causal softmax, in-register; zero-fill to 256-aligned boundary
__launch_bounds__(256)
__global__ void softmax_rows(bf16* __restrict__ P)
{
    const int wid = threadIdx.x >> 6, lane = threadIdx.x & 63;
    const int r = blockIdx.x * 4 + wid, b = blockIdx.y;
    bf16* row = P + ((size_t)b * 2048 + r) * 2048;
    const int nv  = r + 1;
    const int rup = (r & ~255) + 256;

    float vals[4][8];
    float m = -1e30f;
    #pragma unroll
    for (int c = 0; c < 4; ++c) {
        const int k0 = c * 512 + lane * 8;
        bf16x8 x = *(const bf16x8*)(row + k0);
        #pragma unroll
        for (int j = 0; j < 8; ++j) {
            float f = (k0 + j < nv) ? bf2f(x[j]) : -1e30f;
            vals[c][j] = f;
            m = fmaxf(m, f);
        }
    }
    #pragma unroll
    for (int o = 32; o; o >>= 1) m = fmaxf(m, __shfl_xor(m, o));

    float sum = 0.f;
    #pragma unroll
    for (int c = 0; c < 4; ++c)
        #pragma unroll
        for (int j = 0; j < 8; ++j) {
            float e = __expf(vals[c][j] - m);   // masked -> exp(-huge) = 0
            vals[c][j] = e;
            sum += e;
        }
    #pragma unroll
    for (int o = 32; o; o >>= 1) sum += __shfl_xor(sum, o);
    const float inv = 1.0f / sum;

    #pragma unroll
    for (int c = 0; c < 4; ++c) {
        const int k0 = c * 512 + lane * 8;
        if (k0 < rup) {
            union { short h[8]; bf16x8 v8; } o;
            #pragma unroll
            for (int j = 0; j < 8; ++j) {
                bf16 hh = __float2bfloat16(vals[c][j] * inv);
                o.h[j] = *(short*)&hh;
            }
            *(bf16x8*)(row + k0) = o.v8;
        }
    }
}

extern "C" void kernel_launch(void* const* d_in, const int* in_sizes, int n_in,
                              void* d_out, int out_size, void* d_ws, size_t ws_size,
                              hipStream_t stream)
{
    const float* v  = (const float*)d_in[0];
    const float* k  = (const float*)d_in[1];
    const float* q  = (const float*)d_in[2];
    const float* wi = (const float*)d_in[3];
    float* out = (float*)d_out;

    char* ws = (char*)d_ws;
    const size_t WT_OFF   = 0;                       // 2 MB
    const size_t PROJ_OFF = WT_OFF + (2u << 20);     // 48 MB
    const size_t VPT_OFF  = PROJ_OFF + (size_t)24576 * 1024 * 2;   // 16 MB
    const size_t XB_OFF   = VPT_OFF + (size_t)4 * 1024 * 2048 * 2; // 48 MB

    bf16* Wt   = (bf16*)(ws + WT_OFF);
    bf16* proj = (bf16*)(ws + PROJ_OFF);   // [q(8192)|k(8192)|v(8192)] x 1024
    bf16* vpT  = (bf16*)(ws + VPT_OFF);    // [4][1024][2048]
    bf16* Xb   = (bf16*)(ws + XB_OFF);     // [24576][1024] bf16 X
    bf16* P    = Xb;                       // P [4][2048][2048] aliases Xb (dead)

    bf16* qp_b = proj;
    bf16* kp_b = proj + (size_t)8192 * 1024;
    bf16* vp_b = proj + (size_t)16384 * 1024;

    (void)hipFuncSetAttribute((const void*)proj_gemm256,
            hipFuncAttributeMaxDynamicSharedMemorySize, 131072);
    (void)hipFuncSetAttribute((const void*)gemm_bn128<1>,
            hipFuncAttributeMaxDynamicSharedMemorySize, 98304);
    (void)hipFuncSetAttribute((const void*)gemm_bn128<2>,
            hipFuncAttributeMaxDynamicSharedMemorySize, 98304);

    transpose_wi<<<dim3(32, 32), 256, 0, stream>>>(wi, Wt);
    convert_qkv<<<2048, 256, 0, stream>>>(q, k, v, Xb);

    // projection: [24576,1024] = Xb @ Wt^T-form (all-gload_lds pipeline)
    proj_gemm256<<<dim3(4, 96), 512, 131072, stream>>>(Xb, Wt, proj);

    transpose_vp<<<dim3(32, 64, 4), 256, 0, stream>>>(vp_b, vpT);

    // scores: per batch [2048,2048] = qp @ kp^T * 1/32, causal skip (128-col tiles)
    gemm_bn128<1><<<dim3(16, 8, 4), 512, 98304, stream>>>(
        qp_b, kp_b, P, nullptr, nullptr,
        1024, 1024, 2048, 1024,
        (long)2048 * 1024, (long)2048 * 1024, (long)2048 * 2048, 0, 0.03125f);

    softmax_rows<<<dim3(512, 4), 256, 0, stream>>>(P);

    // PV: per batch [2048,1024] = P @ vpT^T-form + qp residual (f32 out)
    gemm_bn128<2><<<dim3(8, 8, 4), 512, 98304, stream>>>(
        P, vpT, nullptr, out, qp_b,
        2048, 2048, 1024, 2048,
        (long)2048 * 2048, (long)1024 * 2048, (long)2048 * 1024, (long)2048 * 1024, 1.0f);
}

// Round 5
// 183.807 us; speedup vs baseline: 1.2186x; 1.0443x over previous
//
#include <hip/hip_runtime.h>
#include <hip/hip_bf16.h>

typedef __hip_bfloat16 bf16;
typedef short bf16x8 __attribute__((ext_vector_type(8)));
typedef float f32x4 __attribute__((ext_vector_type(4)));

#define HT 16384   // bf16 half-tile bytes: 128 rows x 64 cols

__device__ __forceinline__ void gload16(const void* g, void* l) {
    __builtin_amdgcn_global_load_lds(
        (const __attribute__((address_space(1))) void*)g,
        (__attribute__((address_space(3))) void*)l, 16, 0, 0);
}

// ---- bf16 half-tile staging (128 rows x 64 cols), slot-indexed (HT units) ----
__device__ __forceinline__ void stage_half(char* lds, const bf16* src, int ld,
                                           int rowbase, int k0, int slotIdx,
                                           int tid)
{
    char* dst = lds + (size_t)slotIdx * HT + tid * 16;
    const int sub = tid >> 3;
    const int cb  = ((tid & 7) ^ (sub & 7)) << 4;
    #pragma unroll
    for (int p = 0; p < 2; ++p) {
        const int row = p * 64 + sub;
        const char* g = (const char*)(src + (size_t)(rowbase + row) * ld + k0) + cb;
        gload16(g, dst + p * 8192);
    }
}

__device__ __forceinline__ bf16x8 ldsfrag(const char* lds, int slotIdx,
                                          int row, int ks, int cb0)
{
    return *(const bf16x8*)(lds + (size_t)slotIdx * HT
                            + row * 128 + (cb0 ^ (ks << 6)));
}

// ======== fused projection: [24576,1024]bf16 = f32[q;k;v] @ Wt^T-form ========
// BM=256 BN=128 BK=64, 8 waves 4Mx2N. LDS/buf: A0 f32 32K @0, A1 f32 32K @32K,
// B bf16 16K @64K; buf stride 80K; total 160 KiB. A staged as f32 via
// global_load_lds (same counted-vmcnt pipeline as proven bf16 kernel),
// f32->bf16 cast at fragment-read time.
__device__ __forceinline__ void stage_Af32(char* base, const float* src,
                                           int rowbase, int k0, int slot, int tid)
{
    char* dst = base + slot * 32768 + tid * 16;
    #pragma unroll
    for (int p = 0; p < 4; ++p) {
        const int s = p * 512 + tid;
        const int row = s >> 4, ch = s & 15;
        const char* g = (const char*)(src + (size_t)(rowbase + row) * 1024 + k0)
                        + ((ch ^ (row & 15)) << 4);
        gload16(g, dst + p * 8192);
    }
}

__device__ __forceinline__ bf16x8 fragAf32(const char* base, int slot,
                                           int row, int ks, int fq)
{
    const char* p0 = base + slot * 32768 + row * 256;
    const int c0 = ks * 8 + fq * 2, r15 = row & 15;
    f32x4 lo = *(const f32x4*)(p0 + ((c0 ^ r15) << 4));
    f32x4 hi = *(const f32x4*)(p0 + (((c0 + 1) ^ r15) << 4));
    union { short h[8]; bf16x8 v; } o;
    #pragma unroll
    for (int e = 0; e < 4; ++e) {
        bf16 a = __float2bfloat16(lo[e]), b = __float2bfloat16(hi[e]);
        o.h[e] = *(short*)&a;
        o.h[4 + e] = *(short*)&b;
    }
    return o.v;
}

__launch_bounds__(512, 2)
__global__ void proj_f32(const float* __restrict__ q, const float* __restrict__ k,
                         const float* __restrict__ v, const bf16* __restrict__ B,
                         bf16* __restrict__ C)
{
    extern __shared__ char lds[];
    // chunked bijective XCD swizzle: each XCD owns 12 contiguous row-panels
    const int orig = blockIdx.y * 8 + blockIdx.x;      // 768 blocks
    const int wk = (orig & 7) * 96 + (orig >> 3);
    const int bi = wk >> 3, bj = wk & 7;               // bi 0..95, bj 0..7
    const int brow = bi * 256, bcol = bj * 128;
    const float* Asrc = (bi < 32) ? q : (bi < 64) ? k : v;
    const int arow = (bi & 31) * 256;

    const int tid  = threadIdx.x;
    const int lane = tid & 63;
    const int w    = tid >> 6;
    const int wm   = w >> 1, wn = w & 1;               // 4M x 2N
    const int fr   = lane & 15, fq = lane >> 4;
    const int cb0  = ((fr & 7) ^ fq) << 4;
    const int slotA = wm >> 1;                         // A0 / A1
    const int rA    = (wm & 1) * 64;
    const int rB    = wn * 64;
    const int NT    = 16;                              // K=1024 / 64

    f32x4 acc[4][4] = {};
    bf16x8 af[4][2], bv[4][2];

#define BBASE(buf) (lds + (buf) * 81920 + 65536)
#define ABASE(buf) (lds + (buf) * 81920)
    // B staged at byte base 65536 within buf: reuse stage_half via slot math
    // (65536 + buf*81920 is a multiple of HT only for buf=0; use raw pointers)
    // stage B manually:
#define STAGE_B(buf, k0)                                                      \
    {                                                                         \
        char* dst_ = BBASE(buf) + tid * 16;                                   \
        const int sub_ = tid >> 3;                                            \
        const int cb_  = ((tid & 7) ^ (sub_ & 7)) << 4;                       \
        _Pragma("unroll") for (int p_ = 0; p_ < 2; ++p_) {                    \
            const int row_ = p_ * 64 + sub_;                                  \
            const char* g_ = (const char*)(B + (size_t)(bcol + row_) * 1024   \
                                           + (k0)) + cb_;                     \
            gload16(g_, dst_ + p_ * 8192);                                    \
        }                                                                     \
    }

    // prologue: B(0), A0(0), A1(0), B(1); complete tile0, keep B(1) in flight
    STAGE_B(0, 0)
    stage_Af32(ABASE(0), Asrc, arow,      0, 0, tid);
    stage_Af32(ABASE(0), Asrc, arow + 128, 0, 1, tid);
    STAGE_B(1, 64)
    asm volatile("s_waitcnt vmcnt(2)" ::: "memory");
    __builtin_amdgcn_s_barrier();

#define QUAD2(m0, n0)                                                         \
    _Pragma("unroll") for (int dm = 0; dm < 2; ++dm)                          \
    _Pragma("unroll") for (int dn = 0; dn < 2; ++dn)                          \
    _Pragma("unroll") for (int ks = 0; ks < 2; ++ks)                          \
        acc[(m0)+dm][(n0)+dn] = __builtin_amdgcn_mfma_f32_16x16x32_bf16(      \
            af[(m0)+dm][ks], bv[(n0)+dn][ks], acc[(m0)+dm][(n0)+dn], 0, 0, 0);

    for (int t = 0; t < NT; ++t) {
        const int buf = t & 1, nbuf = buf ^ 1;
        const int k1 = min(t + 1, NT - 1) << 6;
        const int k2 = min(t + 2, NT - 1) << 6;

        // ph0: read af01 + bv01; stage (t+1).A0
        #pragma unroll
        for (int m = 0; m < 2; ++m)
            #pragma unroll
            for (int ks = 0; ks < 2; ++ks)
                af[m][ks] = fragAf32(ABASE(buf), slotA, rA + m * 16 + fr, ks, fq);
        #pragma unroll
        for (int n = 0; n < 2; ++n)
            #pragma unroll
            for (int ks = 0; ks < 2; ++ks)
                bv[n][ks] = ldsfrag(BBASE(buf), 0, rB + n * 16 + fr, ks, cb0);
        stage_Af32(ABASE(nbuf), Asrc, arow, k1, 0, tid);
        __builtin_amdgcn_s_barrier();
        __builtin_amdgcn_s_setprio(1);
        QUAD2(0, 0)
        __builtin_amdgcn_s_setprio(0);
        __builtin_amdgcn_s_barrier();

        // ph1: read bv23; stage (t+1).A1
        #pragma unroll
        for (int n = 2; n < 4; ++n)
            #pragma unroll
            for (int ks = 0; ks < 2; ++ks)
                bv[n][ks] = ldsfrag(BBASE(buf), 0, rB + n * 16 + fr, ks, cb0);
        stage_Af32(ABASE(nbuf), Asrc, arow + 128, k1, 1, tid);
        __builtin_amdgcn_s_barrier();
        __builtin_amdgcn_s_setprio(1);
        QUAD2(0, 2)
        __builtin_amdgcn_s_setprio(0);
        __builtin_amdgcn_s_barrier();

        // ph2: read af23; stage (t+2).B
        #pragma unroll
        for (int m = 2; m < 4; ++m)
            #pragma unroll
            for (int ks = 0; ks < 2; ++ks)
                af[m][ks] = fragAf32(ABASE(buf), slotA, rA + m * 16 + fr, ks, fq);
        STAGE_B(buf, k2)
        __builtin_amdgcn_s_barrier();
        __builtin_amdgcn_s_setprio(1);
        QUAD2(2, 2)
        __builtin_amdgcn_s_setprio(0);
        __builtin_amdgcn_s_barrier();

        // ph3: last quadrant; counted vmcnt leaves (t+2).B in flight
        __builtin_amdgcn_s_setprio(1);
        QUAD2(2, 0)
        __builtin_amdgcn_s_setprio(0);
        asm volatile("s_waitcnt vmcnt(2)" ::: "memory");
        __builtin_amdgcn_s_barrier();
    }
#undef QUAD2
#undef STAGE_B
#undef ABASE
#undef BBASE

    #pragma unroll
    for (int mf = 0; mf < 4; ++mf) {
        const int r0 = brow + wm * 64 + mf * 16 + fq * 4;
        #pragma unroll
        for (int nf = 0; nf < 4; ++nf) {
            const int c = bcol + wn * 64 + nf * 16 + fr;
            #pragma unroll
            for (int j = 0; j < 4; ++j)
                C[(size_t)(r0 + j) * 1024 + c] = __float2bfloat16(acc[mf][nf][j]);
        }
    }
}

// ====== BM=256 x BN=128 GEMM: MODE 1 = scores (causal), MODE 2 = PV ======
// Slots/buf: A0=0 A1=1 B=2 (96 KiB total). 8 waves 4Mx2N, wave tile 64x64.
template<int MODE>
__launch_bounds__(512, 2)
__global__ void gemm_bn128(const bf16* __restrict__ A, const bf16* __restrict__ B,
                           bf16* __restrict__ Cb, float* __restrict__ Cf,
                           const bf16* __restrict__ Res,
                           int lda, int ldb, int ldc, int K,
                           long sA, long sB, long sC, long sR, float scale)
{
    extern __shared__ char lds[];
    int bi, bj;
    if (MODE == 1) { bj = blockIdx.x; bi = blockIdx.y; if (bj > 2 * bi + 1) return; }
    else           { bi = blockIdx.x; bj = blockIdx.y; }
    const int bz = blockIdx.z;
    A += (size_t)bz * sA;
    B += (size_t)bz * sB;
    const int brow = bi * 256, bcol = bj * 128;

    const int tid  = threadIdx.x;
    const int lane = tid & 63;
    const int w    = tid >> 6;
    const int wm   = w >> 1, wn = w & 1;
    const int fr   = lane & 15, fq = lane >> 4;
    const int cb0  = ((fr & 7) ^ fq) << 4;
    const int slotA = wm >> 1;
    const int rA    = (wm & 1) * 64;
    const int rB    = wn * 64;

    const int kmax = (MODE == 2) ? (brow + 256) : K;
    const int NT   = kmax >> 6;     // 4..32

    f32x4 acc[4][4] = {};
    bf16x8 af[4][2], bv[4][2];

    // prologue: tile0 {B,A0,A1} + tile1 {B}
    stage_half(lds, B, ldb, bcol,       0, 2, tid);
    stage_half(lds, A, lda, brow,       0, 0, tid);
    stage_half(lds, A, lda, brow + 128, 0, 1, tid);
    stage_half(lds, B, ldb, bcol,      64, 5, tid);
    asm volatile("s_waitcnt vmcnt(2)" ::: "memory");
    __builtin_amdgcn_s_barrier();

#define QUAD2(m0, n0)                                                         \
    _Pragma("unroll") for (int dm = 0; dm < 2; ++dm)                          \
    _Pragma("unroll") for (int dn = 0; dn < 2; ++dn)                          \
    _Pragma("unroll") for (int ks = 0; ks < 2; ++ks)                          \
        acc[(m0)+dm][(n0)+dn] = __builtin_amdgcn_mfma_f32_16x16x32_bf16(      \
            af[(m0)+dm][ks], bv[(n0)+dn][ks], acc[(m0)+dm][(n0)+dn], 0, 0, 0);

    for (int t = 0; t < NT; ++t) {
        const int buf = t & 1, nbuf = buf ^ 1;
        const int k1 = min(t + 1, NT - 1) << 6;
        const int k2 = min(t + 2, NT - 1) << 6;

        // ph0: read af01 + bv01; stage (t+1).A0
        #pragma unroll
        for (int m = 0; m < 2; ++m)
            #pragma unroll
            for (int ks = 0; ks < 2; ++ks)
                af[m][ks] = ldsfrag(lds, buf * 3 + slotA, rA + m * 16 + fr, ks, cb0);
        #pragma unroll
        for (int n = 0; n < 2; ++n)
            #pragma unroll
            for (int ks = 0; ks < 2; ++ks)
                bv[n][ks] = ldsfrag(lds, buf * 3 + 2, rB + n * 16 + fr, ks, cb0);
        stage_half(lds, A, lda, brow, k1, nbuf * 3 + 0, tid);
        __builtin_amdgcn_s_barrier();
        __builtin_amdgcn_s_setprio(1);
        QUAD2(0, 0)
        __builtin_amdgcn_s_setprio(0);
        __builtin_amdgcn_s_barrier();

        // ph1: read bv23; stage (t+1).A1
        #pragma unroll
        for (int n = 2; n < 4; ++n)
            #pragma unroll
            for (int ks = 0; ks < 2; ++ks)
                bv[n][ks] = ldsfrag(lds, buf * 3 + 2, rB + n * 16 + fr, ks, cb0);
        stage_half(lds, A, lda, brow + 128, k1, nbuf * 3 + 1, tid);
        __builtin_amdgcn_s_barrier();
        __builtin_amdgcn_s_setprio(1);
        QUAD2(0, 2)
        __builtin_amdgcn_s_setprio(0);
        __builtin_amdgcn_s_barrier();

        // ph2: read af23; stage (t+2).B
        #pragma unroll
        for (int m = 2; m < 4; ++m)
            #pragma unroll
            for (int ks = 0; ks < 2; ++ks)
                af[m][ks] = ldsfrag(lds, buf * 3 + slotA, rA + m * 16 + fr, ks, cb0);
        stage_half(lds, B, ldb, bcol, k2, buf * 3 + 2, tid);
        __builtin_amdgcn_s_barrier();
        __builtin_amdgcn_s_setprio(1);
        QUAD2(2, 2)
        __builtin_amdgcn_s_setprio(0);
        __builtin_amdgcn_s_barrier();

        // ph3: remaining quadrant; counted vmcnt leaves (t+2).B in flight
        __builtin_amdgcn_s_setprio(1);
        QUAD2(2, 0)
        __builtin_amdgcn_s_setprio(0);
        asm volatile("s_waitcnt vmcnt(2)" ::: "memory");
        __builtin_amdgcn_s_barrier();
    }
#undef QUAD2

    if (MODE == 1) {
        bf16* C = Cb + (size_t)bz * sC;
        #pragma unroll
        for (int mf = 0; mf < 4; ++mf) {
            const int r0 = brow + wm * 64 + mf * 16 + fq * 4;
            #pragma unroll
            for (int nf = 0; nf < 4; ++nf) {
                const int c = bcol + wn * 64 + nf * 16 + fr;
                #pragma unroll
                for (int j = 0; j < 4; ++j)
                    C[(size_t)(r0 + j) * ldc + c] =
                        __float2bfloat16(acc[mf][nf][j] * scale);
            }
        }
    } else {
        float* C = Cf + (size_t)bz * sC;
        const bf16* R = Res + (size_t)bz * sR;
        #pragma unroll
        for (int mf = 0; mf < 4; ++mf) {
            const int r0 = brow + wm * 64 + mf * 16 + fq * 4;
            #pragma unroll
            for (int nf = 0; nf < 4; ++nf) {
                const int c = bcol + wn * 64 + nf * 16 + fr;
                #pragma unroll
                for (int j = 0; j < 4; ++j)
                    C[(size_t)(r0 + j) * ldc + c] = acc[mf][nf][j] +
                        __bfloat162float(R[(size_t)(r0 + j) * ldc + c]);
            }
        }
    }
}

// Wt[n][k] = bf16(wi[k][n]),  1024x1024
__global__ void transpose_wi(const float* __restrict__ wi, bf16* __restrict__ Wt)
{
    __shared__ float t[32][33];
    const int n0 = blockIdx.x * 32, k0 = blockIdx.y * 32;
    const int lx = threadIdx.x & 31, ly = threadIdx.x >> 5;
    for (int i = ly; i < 32; i += 8)
        t[i][lx] = wi[(size_t)(k0 + i) * 1024 + n0 + lx];
    __syncthreads();
    for (int i = ly; i < 32; i += 8)
        Wt[(size_t)(n0 + i) * 1024 + k0 + lx] = __float2bfloat16(t[lx][i]);
}

// vpT[b][d][s] = vp[b][s][d]
__global__ void transpose_vp(const bf16* __restrict__ vp, bf16* __restrict__ vpT)
{
    __shared__ bf16 t[32][33];
    const int b = blockIdx.z;
    const int d0 = blockIdx.x * 32, s0 = blockIdx.y * 32;
    const bf16* src = vp + (size_t)b * 2048 * 1024;
    bf16* dst = vpT + (size_t)b * 1024 * 2048;
    const int lx = threadIdx.x & 31, ly = threadIdx.x >> 5;
    for (int i = ly; i < 32; i += 8)
        t[i][lx] = src[(size_t)(s0 + i) * 1024 + d0 + lx];
    __syncthreads();
    for (int i = ly; i < 32; i += 8)
        dst[(size_t)(d0 + i) * 2048 + s0 + lx] = t[lx][i];
}

__device__ __forceinline__ float bf2f(short s) {
    union { float f; unsigned u; } c;
    c.u = ((unsigned)(unsigned short)s) << 16;
    return c.f;
}

// wave-per-row causal softmax, causal-bounded loads/stores
__launch_bounds__(256)
__global__ void softmax_rows(bf16* __restrict__ P)
{
    const int wid = threadIdx.x >> 6, lane = threadIdx.x & 63;
    const int r = blockIdx.x * 4 + wid, b = blockIdx.y;
    bf16* row = P + ((size_t)b * 2048 + r) * 2048;
    const int nv  = r + 1;
    const int rup = (r & ~255) + 256;

    float vals[4][8];
    float m = -1e30f;
    #pragma unroll
    for (int c = 0; c < 4; ++c) {
        const int k0 = c * 512 + lane * 8;
        if (k0 < rup) {
            bf16x8 x = *(const bf16x8*)(row + k0);
            #pragma unroll
            for (int j = 0; j < 8; ++j) {
                float f = (k0 + j < nv) ? bf2f(x[j]) : -1e30f;
                vals[c][j] = f;
                m = fmaxf(m, f);
            }
        } else {
            #pragma unroll
            for (int j = 0; j < 8; ++j) vals[c][j] = -1e30f;
        }
    }
    #pragma unroll
    for (int o = 32; o; o >>= 1) m = fmaxf(m, __shfl_xor(m, o));

    float sum = 0.f;
    #pragma unroll
    for (int c = 0; c < 4; ++c)
        #pragma unroll
        for (int j = 0; j < 8; ++j) {
            float e = __expf(vals[c][j] - m);   // masked -> exp(-huge) = 0
            vals[c][j] = e;
            sum += e;
        }
    #pragma unroll
    for (int o = 32; o; o >>= 1) sum += __shfl_xor(sum, o);
    const float inv = 1.0f / sum;

    #pragma unroll
    for (int c = 0; c < 4; ++c) {
        const int k0 = c * 512 + lane * 8;
        if (k0 < rup) {
            union { short h[8]; bf16x8 v8; } o;
            #pragma unroll
            for (int j = 0; j < 8; ++j) {
                bf16 hh = __float2bfloat16(vals[c][j] * inv);
                o.h[j] = *(short*)&hh;
            }
            *(bf16x8*)(row + k0) = o.v8;
        }
    }
}

extern "C" void kernel_launch(void* const* d_in, const int* in_sizes, int n_in,
                              void* d_out, int out_size, void* d_ws, size_t ws_size,
                              hipStream_t stream)
{
    const float* v  = (const float*)d_in[0];
    const float* k  = (const float*)d_in[1];
    const float* q  = (const float*)d_in[2];
    const float* wi = (const float*)d_in[3];
    float* out = (float*)d_out;

    char* ws = (char*)d_ws;
    const size_t WT_OFF   = 0;                       // 2 MB
    const size_t PROJ_OFF = WT_OFF + (2u << 20);     // 48 MB
    const size_t VPT_OFF  = PROJ_OFF + (size_t)24576 * 1024 * 2;   // 16 MB
    const size_t P_OFF    = VPT_OFF + (size_t)4 * 1024 * 2048 * 2; // 32 MB

    bf16* Wt   = (bf16*)(ws + WT_OFF);
    bf16* proj = (bf16*)(ws + PROJ_OFF);   // [q(8192)|k(8192)|v(8192)] x 1024
    bf16* vpT  = (bf16*)(ws + VPT_OFF);    // [4][1024][2048]
    bf16* P    = (bf16*)(ws + P_OFF);      // [4][2048][2048]

    bf16* qp_b = proj;
    bf16* kp_b = proj + (size_t)8192 * 1024;
    bf16* vp_b = proj + (size_t)16384 * 1024;

    (void)hipFuncSetAttribute((const void*)proj_f32,
            hipFuncAttributeMaxDynamicSharedMemorySize, 163840);
    (void)hipFuncSetAttribute((const void*)gemm_bn128<1>,
            hipFuncAttributeMaxDynamicSharedMemorySize, 98304);
    (void)hipFuncSetAttribute((const void*)gemm_bn128<2>,
            hipFuncAttributeMaxDynamicSharedMemorySize, 98304);

    transpose_wi<<<dim3(32, 32), 256, 0, stream>>>(wi, Wt);

    // fused convert+projection: f32 q,k,v staged directly via global_load_lds
    proj_f32<<<dim3(8, 96), 512, 163840, stream>>>(q, k, v, Wt, proj);

    transpose_vp<<<dim3(32, 64, 4), 256, 0, stream>>>(vp_b, vpT);

    // scores: per batch [2048,2048] = qp @ kp^T * 1/32, causal skip (128-col tiles)
    gemm_bn128<1><<<dim3(16, 8, 4), 512, 98304, stream>>>(
        qp_b, kp_b, P, nullptr, nullptr,
        1024, 1024, 2048, 1024,
        (long)2048 * 1024, (long)2048 * 1024, (long)2048 * 2048, 0, 0.03125f);

    softmax_rows<<<dim3(512, 4), 256, 0, stream>>>(P);

    // PV: per batch [2048,1024] = P @ vpT^T-form + qp residual (f32 out)
    gemm_bn128<2><<<dim3(8, 8, 4), 512, 98304, stream>>>(
        P, vpT, nullptr, out, qp_b,
        2048, 2048, 1024, 2048,
        (long)2048 * 2048, (long)1024 * 2048, (long)2048 * 1024, (long)2048 * 1024, 1.0f);
}